// Round 18
// baseline (196.589 us; speedup 1.0000x reference)
//
#include <hip/hip_runtime.h>
#include <hip/hip_bf16.h>

#define BB 4096
#define SZ 32
#define DD 10000
#define DPAD 10240
#define NMOD 64
#define NROWS_B 192   // cluster(64) + Mh(64) + Ml(64)
#define KSPLIT 4
#define KSEG 2560     // DPAD / KSPLIT
#define NWORDS 160    // DPAD/64 packed words per row
#define STEPS 40      // KSEG/64

// ws layout (bytes)
#define WS_BK_OFF     0u                 // 160*192*64*2 = 3.93 MB
#define WS_PACK_OFF   (4u << 20)         // 160*4096*8 = 5.24 MB
#define WS_CPART_OFF  9437184u           // 4*4096*192*4 = 12.6 MB (end 22.0 MB)

typedef __attribute__((ext_vector_type(4))) float f32x4;
typedef __attribute__((ext_vector_type(8))) short short8;

static __device__ __forceinline__ ushort f2bf(float f) {
    unsigned u = __builtin_bit_cast(unsigned, f);
    unsigned r = (u + 0x7fffu + ((u >> 16) & 1u)) >> 16;   // RNE
    return (ushort)r;
}

// sign pipeline: 1 iff cosf(t+bk)*sinf(t) > 0, else 0 (covers ==0 -> -1).
static __device__ __forceinline__ int sign_pm(float t, float bk) {
    if (t == 0.0f) return 0;
    const double INV_PI_D = 0.31830988618379067153776752674503;
    float v = t + bk;
    long long n1 = (long long)floor((double)t * INV_PI_D);
    long long n2 = (long long)floor(fma((double)v, INV_PI_D, 0.5));
    return (int)(((n1 + n2) & 1LL) ^ 1LL);
}

// expand 8 packed bits (bit=1 -> +1.0bf16, 0 -> -1.0bf16) into short8
static __device__ __forceinline__ short8 expand8(unsigned b) {
    unsigned nb = ~b;
    unsigned r0 = 0x3F803F80u | ((nb & 1u) << 15) | ((nb & 2u) << 30);
    unsigned r1 = 0x3F803F80u | (((nb >> 2) & 1u) << 15) | (((nb >> 2) & 2u) << 30);
    unsigned r2 = 0x3F803F80u | (((nb >> 4) & 1u) << 15) | (((nb >> 4) & 2u) << 30);
    unsigned r3 = 0x3F803F80u | (((nb >> 6) & 1u) << 15) | (((nb >> 6) & 2u) << 30);
    uint4 u = make_uint4(r0, r1, r2, r3);
    return __builtin_bit_cast(short8, u);
}

// ---------------- K0: build Bk [160][192][64] bf16 (cluster, Mh, Ml) ------
__global__ __launch_bounds__(256) void k0_build_B(
        const float* __restrict__ M, const float* __restrict__ cluster,
        ushort* __restrict__ Bk) {
    int k = blockIdx.x * 256 + threadIdx.x;   // 0..10239
    int row = blockIdx.y;                      // 0..191
    ushort u = 0;
    if (k < DD) {
        if (row < 64) {
            u = f2bf(cluster[(size_t)row * DD + k]);
        } else {
            float m = M[(size_t)(row & 63) * DD + k];
            ushort mh = f2bf(m);
            if (row < 128) {
                u = mh;
            } else {
                float mhf = __builtin_bit_cast(float, (unsigned)mh << 16);
                u = f2bf(m - mhf);
            }
        }
    }
    int step = k >> 6, kk = k & 63;
    Bk[((size_t)step * NROWS_B + row) * 64 + kk] = u;
}

// ---------------- K1: encode (T_G ordering), 4 columns/thread -------------
// x rows wave-uniform -> SGPR s_load double-buffer; per row-load: 128 FMA
// + 4 sign_pm (latency hidden). W frags (4x32 f32) resident in VGPRs.
__global__ __launch_bounds__(256, 2) void k1_enc(
        const float* __restrict__ x, const float* __restrict__ W,
        const float* __restrict__ bias, float* __restrict__ enc_out,
        unsigned long long* __restrict__ packedT) {
    const int tid = threadIdx.x;
    const int lane = tid & 63;
    const int wv = tid >> 6;
    const int i0 = blockIdx.y * 64;

    int kc[4]; bool vl[4]; float bk[4];
    float4 w4[4][8];
    #pragma unroll
    for (int j = 0; j < 4; ++j) {
        kc[j] = blockIdx.x * 1024 + j * 256 + tid;
        vl[j] = kc[j] < DD;
        int kw = vl[j] ? kc[j] : 0;
        const float4* wg = reinterpret_cast<const float4*>(W) + (size_t)kw * 8;
        #pragma unroll
        for (int q = 0; q < 8; ++q) w4[j][q] = wg[q];
        bk[j] = bias[kw];
    }
    const int colg0 = blockIdx.x * 16 + wv;   // + j*4

    const float4* xb4 = reinterpret_cast<const float4*>(x + (size_t)i0 * SZ);

    float4 xa[8], xb[8];
    #pragma unroll
    for (int q = 0; q < 8; ++q) xa[q] = xb4[q];     // row 0

    auto dorow = [&](int i, const float4* xr) {
        float g[4][4];
        #pragma unroll
        for (int j = 0; j < 4; ++j)
            #pragma unroll
            for (int a = 0; a < 4; ++a) g[j][a] = 0.f;
        #pragma unroll
        for (int q = 0; q < 8; ++q) {
            float4 xc = xr[q];
            #pragma unroll
            for (int j = 0; j < 4; ++j) {
                g[j][0] = fmaf(w4[j][q].x, xc.x, g[j][0]);
                g[j][1] = fmaf(w4[j][q].y, xc.y, g[j][1]);
                g[j][2] = fmaf(w4[j][q].z, xc.z, g[j][2]);
                g[j][3] = fmaf(w4[j][q].w, xc.w, g[j][3]);
            }
        }
        #pragma unroll
        for (int j = 0; j < 4; ++j) {
            float t = (g[j][0] + g[j][1]) + (g[j][2] + g[j][3]);
            int e = vl[j] ? sign_pm(t, bk[j]) : 0;
            unsigned long long bal = __ballot(e);
            if (lane == 0) packedT[(size_t)(colg0 + j * 4) * BB + (i0 + i)] = bal;
            if (vl[j]) enc_out[(size_t)(i0 + i) * DD + kc[j]] = e ? 1.f : -1.f;
        }
    };

    for (int i = 0; i < 64; i += 2) {
        #pragma unroll
        for (int q = 0; q < 8; ++q) xb[q] = xb4[(i + 1) * 8 + q];
        dorow(i, xa);
        if (i + 2 < 64) {
            #pragma unroll
            for (int q = 0; q < 8; ++q) xa[q] = xb4[(i + 2) * 8 + q];
        }
        dorow(i + 1, xb);
    }
}

// ---------------- K2: fragment-direct MFMA GEMM (no LDS, no barriers) -----
// grid (128 row-groups of 32, 4 segs) = 512 blocks (2/CU), 256 thr = 4 waves
// = 4 col-groups of 48 cols (cluster + Mh + Ml all via MFMA).
__global__ __launch_bounds__(256, 2) void k2_gemm(
        const unsigned long long* __restrict__ packedT,  // [160][4096]
        const ushort* __restrict__ Bk,                   // [160][192][64]
        float* __restrict__ Cpart) {
    const int tid = threadIdx.x;
    const int wid = tid >> 6;       // col-group 0..3
    const int lane = tid & 63;
    const int fr = lane & 15;
    const int fg = lane >> 4;

    const int row0 = blockIdx.x * 32;
    const int seg = blockIdx.y;
    const int wcol = wid * 48;

    const unsigned long long* pA = packedT + (size_t)(seg * STEPS) * BB + row0 + fr;
    const ushort* pB = Bk + ((size_t)(seg * STEPS) * NROWS_B + wcol + fr) * 64 + fg * 8;

    f32x4 acc[2][3] = {};
    unsigned long long aw0[2], aw1[2];
    uint4 b0[3][2], b1[3][2];

#define LOADA(dst, s)                                         \
    _Pragma("unroll")                                         \
    for (int mt = 0; mt < 2; ++mt)                            \
        dst[mt] = pA[(size_t)(s) * BB + mt * 16];

#define LOADB(dst, s)                                         \
    _Pragma("unroll")                                         \
    for (int n = 0; n < 3; ++n) {                             \
        const ushort* p = pB + ((size_t)(s) * NROWS_B + n * 16) * 64; \
        dst[n][0] = *reinterpret_cast<const uint4*>(p);       \
        dst[n][1] = *reinterpret_cast<const uint4*>(p + 32);  \
    }

#define COMPUTE(aw, bf)                                       \
    _Pragma("unroll")                                         \
    for (int mt = 0; mt < 2; ++mt) {                          \
        unsigned lo = (unsigned)aw[mt];                       \
        unsigned hi = (unsigned)(aw[mt] >> 32);               \
        short8 af0 = expand8((lo >> (fg * 8)) & 0xffu);       \
        short8 af1 = expand8((hi >> (fg * 8)) & 0xffu);       \
        _Pragma("unroll")                                     \
        for (int n = 0; n < 3; ++n) {                         \
            acc[mt][n] = __builtin_amdgcn_mfma_f32_16x16x32_bf16( \
                af0, __builtin_bit_cast(short8, bf[n][0]), acc[mt][n], 0, 0, 0); \
            acc[mt][n] = __builtin_amdgcn_mfma_f32_16x16x32_bf16( \
                af1, __builtin_bit_cast(short8, bf[n][1]), acc[mt][n], 0, 0, 0); \
        }                                                     \
    }

    LOADA(aw0, 0)
    LOADB(b0, 0)

    for (int s = 0; s < STEPS; s += 2) {
        LOADA(aw1, s + 1)
        LOADB(b1, s + 1)
        COMPUTE(aw0, b0)
        if (s + 2 < STEPS) {
            LOADA(aw0, s + 2)
            LOADB(b0, s + 2)
        }
        COMPUTE(aw1, b1)
    }

    #pragma unroll
    for (int mt = 0; mt < 2; ++mt)
        #pragma unroll
        for (int n = 0; n < 3; ++n)
            #pragma unroll
            for (int r = 0; r < 4; ++r) {
                int grow = row0 + mt * 16 + fg * 4 + r;
                int col = wcol + n * 16 + fr;
                Cpart[((size_t)seg * BB + grow) * NROWS_B + col] = acc[mt][n][r];
            }
#undef LOADA
#undef LOADB
#undef COMPUTE
}

// ---------------- K3: reduce partials + softmax + combine ----------------
__global__ __launch_bounds__(256) void k3_final(
        const float* __restrict__ Cpart, float* __restrict__ res) {
    const int wid = threadIdx.x >> 6;
    const int lane = threadIdx.x & 63;
    const int row = blockIdx.x * 4 + wid;

    float s = 0.f, mh = 0.f, ml = 0.f;
    #pragma unroll
    for (int seg = 0; seg < KSPLIT; ++seg) {
        const float* base = Cpart + ((size_t)seg * BB + row) * NROWS_B;
        s += base[lane];
        mh += base[64 + lane];
        ml += base[128 + lane];
    }
    float sim = s * 1e-4f;          // exact norms: 100 * 100
    float mr = mh + ml;

    float mx = sim;
    #pragma unroll
    for (int o = 32; o; o >>= 1) mx = fmaxf(mx, __shfl_xor(mx, o, 64));
    float e = expf(sim - mx);
    float num = e * mr;
    float Z = e;
    #pragma unroll
    for (int o = 32; o; o >>= 1) {
        Z += __shfl_xor(Z, o, 64);
        num += __shfl_xor(num, o, 64);
    }
    if (lane == 0) res[row] = num / Z;
}

extern "C" void kernel_launch(void* const* d_in, const int* in_sizes, int n_in,
                              void* d_out, int out_size, void* d_ws, size_t ws_size,
                              hipStream_t stream) {
    const float* x = (const float*)d_in[0];
    const float* W = (const float*)d_in[1];
    const float* bias = (const float*)d_in[2];
    const float* M = (const float*)d_in[3];
    const float* cluster = (const float*)d_in[4];

    float* res = (float*)d_out;            // [4096]
    float* enc = (float*)d_out + BB;       // [4096][10000]

    ushort* Bk = (ushort*)((char*)d_ws + WS_BK_OFF);
    unsigned long long* packedT = (unsigned long long*)((char*)d_ws + WS_PACK_OFF);
    float* Cpart = (float*)((char*)d_ws + WS_CPART_OFF);

    k0_build_B<<<dim3(40, NROWS_B), 256, 0, stream>>>(M, cluster, Bk);
    k1_enc<<<dim3(10, 64), 256, 0, stream>>>(x, W, bias, enc, packedT);
    k2_gemm<<<dim3(128, KSPLIT), 256, 0, stream>>>(packedT, Bk, Cpart);
    k3_final<<<BB / 4, 256, 0, stream>>>(Cpart, res);
}

// Round 19
// 158.237 us; speedup vs baseline: 1.2424x; 1.2424x over previous
//
#include <hip/hip_runtime.h>
#include <hip/hip_bf16.h>

#define BB 4096
#define SZ 32
#define DD 10000
#define DPAD 10240
#define NMOD 64
#define NROWS_B 192   // cluster(64) + Mh(64) + Ml(64)
#define KSPLIT 4
#define KSEG 2560     // DPAD / KSPLIT
#define NWORDS 160    // DPAD/64 packed words per row
#define STEPS 40      // KSEG/64

// ws layout (bytes)
#define WS_BK_OFF     0u                 // 160*192*64*2 = 3.93 MB
#define WS_PACK_OFF   (4u << 20)         // 160*4096*8 = 5.24 MB
#define WS_CPART_OFF  9437184u           // 4*4096*192*4 = 12.6 MB (end 22.0 MB)

typedef __attribute__((ext_vector_type(4))) float f32x4;
typedef __attribute__((ext_vector_type(8))) short short8;

static __device__ __forceinline__ ushort f2bf(float f) {
    unsigned u = __builtin_bit_cast(unsigned, f);
    unsigned r = (u + 0x7fffu + ((u >> 16) & 1u)) >> 16;   // RNE
    return (ushort)r;
}

// sign pipeline: 1 iff cosf(t+bk)*sinf(t) > 0, else 0 (covers ==0 -> -1).
static __device__ __forceinline__ int sign_pm(float t, float bk) {
    if (t == 0.0f) return 0;
    const double INV_PI_D = 0.31830988618379067153776752674503;
    float v = t + bk;
    long long n1 = (long long)floor((double)t * INV_PI_D);
    long long n2 = (long long)floor(fma((double)v, INV_PI_D, 0.5));
    return (int)(((n1 + n2) & 1LL) ^ 1LL);
}

// expand 8 packed bits (bit=1 -> +1.0bf16, 0 -> -1.0bf16) into short8
static __device__ __forceinline__ short8 expand8(unsigned b) {
    unsigned nb = ~b;
    unsigned r0 = 0x3F803F80u | ((nb & 1u) << 15) | ((nb & 2u) << 30);
    unsigned r1 = 0x3F803F80u | (((nb >> 2) & 1u) << 15) | (((nb >> 2) & 2u) << 30);
    unsigned r2 = 0x3F803F80u | (((nb >> 4) & 1u) << 15) | (((nb >> 4) & 2u) << 30);
    unsigned r3 = 0x3F803F80u | (((nb >> 6) & 1u) << 15) | (((nb >> 6) & 2u) << 30);
    uint4 u = make_uint4(r0, r1, r2, r3);
    return __builtin_bit_cast(short8, u);
}

// ---------------- K0: build Bk [160][192][64] bf16 (cluster, Mh, Ml) ------
__global__ __launch_bounds__(256) void k0_build_B(
        const float* __restrict__ M, const float* __restrict__ cluster,
        ushort* __restrict__ Bk) {
    int k = blockIdx.x * 256 + threadIdx.x;   // 0..10239
    int row = blockIdx.y;                      // 0..191
    ushort u = 0;
    if (k < DD) {
        if (row < 64) {
            u = f2bf(cluster[(size_t)row * DD + k]);
        } else {
            float m = M[(size_t)(row & 63) * DD + k];
            ushort mh = f2bf(m);
            if (row < 128) {
                u = mh;
            } else {
                float mhf = __builtin_bit_cast(float, (unsigned)mh << 16);
                u = f2bf(m - mhf);
            }
        }
    }
    int step = k >> 6, kk = k & 63;
    Bk[((size_t)step * NROWS_B + row) * 64 + kk] = u;
}

// ---------------- K1: encode (T_G ordering) -------------------------------
// thread = column k. W row loaded ONCE via a single asm block (8x
// global_load_dwordx4 + waitcnt inside) -> outputs are pinned in VGPRs
// (asm results cannot be rematerialized). x rows wave-uniform -> SGPR
// s_load double-buffer. Row loop: pure VALU.
__global__ __launch_bounds__(256, 2) void k1_enc(
        const float* __restrict__ x, const float* __restrict__ W,
        const float* __restrict__ bias, float* __restrict__ enc_out,
        unsigned long long* __restrict__ packedT) {
    const int tid = threadIdx.x;
    const int k = blockIdx.x * 256 + tid;
    const bool valid = (k < DD);
    const int kw = valid ? k : 0;
    const int lane = tid & 63;
    const int colg = blockIdx.x * 4 + (tid >> 6);   // packed word 0..159
    const int i0 = blockIdx.y * 64;

    float4 w0, w1, w2, w3, w4_, w5, w6, w7;
    {
        const float* wp = W + (size_t)kw * SZ;
        asm volatile(
            "global_load_dwordx4 %0, %8, off\n\t"
            "global_load_dwordx4 %1, %8, off offset:16\n\t"
            "global_load_dwordx4 %2, %8, off offset:32\n\t"
            "global_load_dwordx4 %3, %8, off offset:48\n\t"
            "global_load_dwordx4 %4, %8, off offset:64\n\t"
            "global_load_dwordx4 %5, %8, off offset:80\n\t"
            "global_load_dwordx4 %6, %8, off offset:96\n\t"
            "global_load_dwordx4 %7, %8, off offset:112\n\t"
            "s_waitcnt vmcnt(0)"
            : "=&v"(w0), "=&v"(w1), "=&v"(w2), "=&v"(w3),
              "=&v"(w4_), "=&v"(w5), "=&v"(w6), "=&v"(w7)
            : "v"(wp));
    }
    const float bk = bias[kw];

    const float4* xb4 = reinterpret_cast<const float4*>(x + (size_t)i0 * SZ);

    float4 xa[8], xb[8];
    #pragma unroll
    for (int q = 0; q < 8; ++q) xa[q] = xb4[q];     // row 0

    auto dorow = [&](int i, const float4* xr) {
        float g0 = 0.f, g1 = 0.f, g2 = 0.f, g3 = 0.f;
        #pragma unroll
        for (int q = 0; q < 8; ++q) {
            const float4 wq = (q == 0) ? w0 : (q == 1) ? w1 : (q == 2) ? w2 :
                              (q == 3) ? w3 : (q == 4) ? w4_ : (q == 5) ? w5 :
                              (q == 6) ? w6 : w7;
            g0 = fmaf(wq.x, xr[q].x, g0);
            g1 = fmaf(wq.y, xr[q].y, g1);
            g2 = fmaf(wq.z, xr[q].z, g2);
            g3 = fmaf(wq.w, xr[q].w, g3);
        }
        float t = (g0 + g1) + (g2 + g3);
        int e = valid ? sign_pm(t, bk) : 0;
        unsigned long long bal = __ballot(e);
        if (lane == 0) packedT[(size_t)colg * BB + (i0 + i)] = bal;
        if (valid) enc_out[(size_t)(i0 + i) * DD + k] = e ? 1.f : -1.f;
    };

    for (int i = 0; i < 64; i += 2) {
        #pragma unroll
        for (int q = 0; q < 8; ++q) xb[q] = xb4[(i + 1) * 8 + q];
        dorow(i, xa);
        if (i + 2 < 64) {
            #pragma unroll
            for (int q = 0; q < 8; ++q) xa[q] = xb4[(i + 2) * 8 + q];
        }
        dorow(i + 1, xb);
    }
}

// ---------------- K2: fragment-direct MFMA GEMM (no LDS, no barriers) -----
// grid (128 row-groups of 32, 4 segs) = 512 blocks (2/CU), 256 thr = 4 waves
// = 4 col-groups of 48 cols (cluster + Mh + Ml all via MFMA).
__global__ __launch_bounds__(256, 2) void k2_gemm(
        const unsigned long long* __restrict__ packedT,  // [160][4096]
        const ushort* __restrict__ Bk,                   // [160][192][64]
        float* __restrict__ Cpart) {
    const int tid = threadIdx.x;
    const int wid = tid >> 6;       // col-group 0..3
    const int lane = tid & 63;
    const int fr = lane & 15;
    const int fg = lane >> 4;

    const int row0 = blockIdx.x * 32;
    const int seg = blockIdx.y;
    const int wcol = wid * 48;

    const unsigned long long* pA = packedT + (size_t)(seg * STEPS) * BB + row0 + fr;
    const ushort* pB = Bk + ((size_t)(seg * STEPS) * NROWS_B + wcol + fr) * 64 + fg * 8;

    f32x4 acc[2][3] = {};
    unsigned long long aw0[2], aw1[2];
    uint4 b0[3][2], b1[3][2];

#define LOADA(dst, s)                                         \
    _Pragma("unroll")                                         \
    for (int mt = 0; mt < 2; ++mt)                            \
        dst[mt] = pA[(size_t)(s) * BB + mt * 16];

#define LOADB(dst, s)                                         \
    _Pragma("unroll")                                         \
    for (int n = 0; n < 3; ++n) {                             \
        const ushort* p = pB + ((size_t)(s) * NROWS_B + n * 16) * 64; \
        dst[n][0] = *reinterpret_cast<const uint4*>(p);       \
        dst[n][1] = *reinterpret_cast<const uint4*>(p + 32);  \
    }

#define COMPUTE(aw, bf)                                       \
    _Pragma("unroll")                                         \
    for (int mt = 0; mt < 2; ++mt) {                          \
        unsigned lo = (unsigned)aw[mt];                       \
        unsigned hi = (unsigned)(aw[mt] >> 32);               \
        short8 af0 = expand8((lo >> (fg * 8)) & 0xffu);       \
        short8 af1 = expand8((hi >> (fg * 8)) & 0xffu);       \
        _Pragma("unroll")                                     \
        for (int n = 0; n < 3; ++n) {                         \
            acc[mt][n] = __builtin_amdgcn_mfma_f32_16x16x32_bf16( \
                af0, __builtin_bit_cast(short8, bf[n][0]), acc[mt][n], 0, 0, 0); \
            acc[mt][n] = __builtin_amdgcn_mfma_f32_16x16x32_bf16( \
                af1, __builtin_bit_cast(short8, bf[n][1]), acc[mt][n], 0, 0, 0); \
        }                                                     \
    }

    LOADA(aw0, 0)
    LOADB(b0, 0)

    for (int s = 0; s < STEPS; s += 2) {
        LOADA(aw1, s + 1)
        LOADB(b1, s + 1)
        COMPUTE(aw0, b0)
        if (s + 2 < STEPS) {
            LOADA(aw0, s + 2)
            LOADB(b0, s + 2)
        }
        COMPUTE(aw1, b1)
    }

    #pragma unroll
    for (int mt = 0; mt < 2; ++mt)
        #pragma unroll
        for (int n = 0; n < 3; ++n)
            #pragma unroll
            for (int r = 0; r < 4; ++r) {
                int grow = row0 + mt * 16 + fg * 4 + r;
                int col = wcol + n * 16 + fr;
                Cpart[((size_t)seg * BB + grow) * NROWS_B + col] = acc[mt][n][r];
            }
#undef LOADA
#undef LOADB
#undef COMPUTE
}

// ---------------- K3: reduce partials + softmax + combine ----------------
__global__ __launch_bounds__(256) void k3_final(
        const float* __restrict__ Cpart, float* __restrict__ res) {
    const int wid = threadIdx.x >> 6;
    const int lane = threadIdx.x & 63;
    const int row = blockIdx.x * 4 + wid;

    float s = 0.f, mh = 0.f, ml = 0.f;
    #pragma unroll
    for (int seg = 0; seg < KSPLIT; ++seg) {
        const float* base = Cpart + ((size_t)seg * BB + row) * NROWS_B;
        s += base[lane];
        mh += base[64 + lane];
        ml += base[128 + lane];
    }
    float sim = s * 1e-4f;          // exact norms: 100 * 100
    float mr = mh + ml;

    float mx = sim;
    #pragma unroll
    for (int o = 32; o; o >>= 1) mx = fmaxf(mx, __shfl_xor(mx, o, 64));
    float e = expf(sim - mx);
    float num = e * mr;
    float Z = e;
    #pragma unroll
    for (int o = 32; o; o >>= 1) {
        Z += __shfl_xor(Z, o, 64);
        num += __shfl_xor(num, o, 64);
    }
    if (lane == 0) res[row] = num / Z;
}

extern "C" void kernel_launch(void* const* d_in, const int* in_sizes, int n_in,
                              void* d_out, int out_size, void* d_ws, size_t ws_size,
                              hipStream_t stream) {
    const float* x = (const float*)d_in[0];
    const float* W = (const float*)d_in[1];
    const float* bias = (const float*)d_in[2];
    const float* M = (const float*)d_in[3];
    const float* cluster = (const float*)d_in[4];

    float* res = (float*)d_out;            // [4096]
    float* enc = (float*)d_out + BB;       // [4096][10000]

    ushort* Bk = (ushort*)((char*)d_ws + WS_BK_OFF);
    unsigned long long* packedT = (unsigned long long*)((char*)d_ws + WS_PACK_OFF);
    float* Cpart = (float*)((char*)d_ws + WS_CPART_OFF);

    k0_build_B<<<dim3(40, NROWS_B), 256, 0, stream>>>(M, cluster, Bk);
    k1_enc<<<dim3(40, 64), 256, 0, stream>>>(x, W, bias, enc, packedT);
    k2_gemm<<<dim3(128, KSPLIT), 256, 0, stream>>>(packedT, Bk, Cpart);
    k3_final<<<BB / 4, 256, 0, stream>>>(Cpart, res);
}